// Round 7
// baseline (269.737 us; speedup 1.0000x reference)
//
#include <hip/hip_runtime.h>
#include <math.h>

#define B 128
#define C 576
#define H 28
#define W 28
#define HW 784
#define NPLANE (B * C)
#define RMROWS 34   // 3 ghost + 28 + 3 ghost

__device__ __forceinline__ float sigm(float z) { return 1.f / (1.f + __expf(-z)); }

__device__ __forceinline__ float4 fmax4(float4 a, float4 b) {
    a.x = fmaxf(a.x, b.x); a.y = fmaxf(a.y, b.y);
    a.z = fmaxf(a.z, b.z); a.w = fmaxf(a.w, b.w);
    return a;
}

// horizontal 7-window max for 4 px: Mv center f4, Lv left f4, Rv right f4
__device__ __forceinline__ float4 hmax13(float4 Mv, float4 Lv, float4 Rv) {
    float mm   = fmaxf(fmaxf(Mv.x, Mv.y), fmaxf(Mv.z, Mv.w));
    float l23  = fmaxf(Lv.z, Lv.w);
    float l123 = fmaxf(Lv.y, l23);
    float r01  = fmaxf(Rv.x, Rv.y);
    float r012 = fmaxf(r01, Rv.z);
    float4 o;
    o.x = fmaxf(l123, mm);
    o.y = fmaxf(l23, fmaxf(mm, Rv.x));
    o.z = fmaxf(Lv.w, fmaxf(mm, r01));
    o.w = fmaxf(mm, r012);
    return o;
}

// full 64-lane sum via DPP (VALU-only, no LDS); total lands in lane 63
__device__ __forceinline__ float dpp_sum64(float v) {
    int t;
    t = __builtin_amdgcn_update_dpp(0, __float_as_int(v), 0x111, 0xf, 0xf, true);  v += __int_as_float(t);
    t = __builtin_amdgcn_update_dpp(0, __float_as_int(v), 0x112, 0xf, 0xf, true);  v += __int_as_float(t);
    t = __builtin_amdgcn_update_dpp(0, __float_as_int(v), 0x114, 0xf, 0xf, true);  v += __int_as_float(t);
    t = __builtin_amdgcn_update_dpp(0, __float_as_int(v), 0x118, 0xf, 0xf, true);  v += __int_as_float(t);
    t = __builtin_amdgcn_update_dpp(0, __float_as_int(v), 0x142, 0xa, 0xf, false); v += __int_as_float(t);
    t = __builtin_amdgcn_update_dpp(0, __float_as_int(v), 0x143, 0xc, 0xf, false); v += __int_as_float(t);
    return v;
}

__device__ __forceinline__ float rl63(float v) {
    return __int_as_float(__builtin_amdgcn_readlane(__float_as_int(v), 63));
}

// wave-internal LDS write->read ordering (same-wave DS ops are in-order;
// fence stops compiler reordering and drains outstanding LDS ops)
__device__ __forceinline__ void wave_lds_fence() {
    asm volatile("s_waitcnt lgkmcnt(0)" ::: "memory");
    __builtin_amdgcn_sched_barrier(0);
}

// ---------------------------------------------------------------------------
// K0: zero accumulators; build orientation masks interleaved as [196][6][4].
// ---------------------------------------------------------------------------
__global__ void k0_init(float* __restrict__ masks, float* __restrict__ acc) {
    int idx = blockIdx.x * 256 + threadIdx.x;
    if (idx < 6 * C) acc[idx] = 0.f;
    if (idx < 6 * HW) {
        int a = idx / HW;
        int p = idx - a * HW;
        int r = p / W;
        int col = p - r * W;
        const float degs[6] = {0.f, 30.f, 45.f, 60.f, 90.f, 135.f};
        float t = degs[a] * 0.017453292519943295f;
        float gy = -1.f + r * (2.f / 27.f);
        float gx = -1.f + col * (2.f / 27.f);
        float perp = gx * (-sinf(t)) + gy * cosf(t);
        float z = perp * (1.f / 0.3f);
        masks[(p >> 2) * 24 + a * 4 + (p & 3)] = expf(-0.5f * z * z);
    }
}

// ---------------------------------------------------------------------------
// K1: one wave per plane; pooling + means + conv + BN partial sums only
//     (orientation moved to K3). x staged inside rm's padded rows.
// ---------------------------------------------------------------------------
__global__ __launch_bounds__(256, 7) void k1_stats(
    const float* __restrict__ x,
    const float* __restrict__ h_w, const float* __restrict__ v_w,
    const float* __restrict__ f_w,
    float* __restrict__ yh, float* __restrict__ yv,
    float* __restrict__ acc)
{
    const int tid = threadIdx.x;
    const int wvi = __builtin_amdgcn_readfirstlane(tid >> 6);  // wave-uniform
    const int l   = tid & 63;
    const int plane = blockIdx.x * 4 + wvi;
    const int c = plane % C;
    const float* xp = x + (size_t)plane * HW;

    __shared__ __align__(16) float uA[4][RMROWS * W];
    __shared__ __align__(16) float cpA[4][196];
    __shared__ __align__(16) float rpA[4][196];
    float* rm  = uA[wvi];
    float* sxv = rm + 3 * W;      // x rows 0..27 live at padded rows 3..30
    float* cp  = cpA[wvi];
    float* rp  = rpA[wvi];

    const int r0 = l / 7;        // 0..6 (valid for l<49)
    const int u  = l - r0 * 7;   // column group 0..6
    const int q  = u * 4;
    const int qL = u ? q - 4 : 0;
    const int qR = (u < 6) ? q + 4 : 24;
    const bool act = (l < 49);

    float4 Mv[4];
    float fs = 0.f, fss = 0.f;

    // P0: load x into regs + padded LDS; col/row partials
    if (act) {
        float4 ca = make_float4(0.f, 0.f, 0.f, 0.f);
        float rw0, rw1, rw2, rw3;
        #pragma unroll
        for (int k = 0; k < 4; ++k) {
            const int unit = l + 49 * k;
            float4 v = ((const float4*)xp)[unit];
            Mv[k] = v;
            ((float4*)sxv)[unit] = v;
            ca.x += v.x; ca.y += v.y; ca.z += v.z; ca.w += v.w;
            float rs = (v.x + v.y) + (v.z + v.w);
            if (k == 0) rw0 = rs; else if (k == 1) rw1 = rs;
            else if (k == 2) rw2 = rs; else rw3 = rs;
        }
        ((float4*)cp)[l] = ca;
        ((float4*)rp)[l] = make_float4(rw0, rw1, rw2, rw3);
    }
    wave_lds_fence();

    // P1: horizontal 7-max; write in place over the row just read (+ ghosts)
    if (act) {
        #pragma unroll
        for (int k = 0; k < 4; ++k) {
            const int r = r0 + 7 * k;
            const float* row = sxv + r * W;
            float4 Lv = *(const float4*)(row + qL);
            float4 Rv = *(const float4*)(row + qR);
            float4 hv = hmax13(Mv[k], Lv, Rv);
            *(float4*)(rm + (r + 3) * W + q) = hv;
            if (k == 0 && r0 == 0) {
                *(float4*)(rm + 0 * W + q) = hv;
                *(float4*)(rm + 1 * W + q) = hv;
                *(float4*)(rm + 2 * W + q) = hv;
            }
            if (k == 3 && r0 == 6) {
                *(float4*)(rm + 31 * W + q) = hv;
                *(float4*)(rm + 32 * W + q) = hv;
                *(float4*)(rm + 33 * W + q) = hv;
            }
        }
    }
    wave_lds_fence();

    // P2: vertical 7-max (immediate offsets into padded rm) -> spots stats
    const float fwc = f_w[c];
    if (act) {
        #pragma unroll
        for (int k = 0; k < 4; ++k) {
            const int r = r0 + 7 * k;
            const float* vb = rm + r * W + q;
            float4 m = *(const float4*)vb;
            m = fmax4(m, *(const float4*)(vb + W));
            m = fmax4(m, *(const float4*)(vb + 2 * W));
            m = fmax4(m, *(const float4*)(vb + 3 * W));
            m = fmax4(m, *(const float4*)(vb + 4 * W));
            m = fmax4(m, *(const float4*)(vb + 5 * W));
            m = fmax4(m, *(const float4*)(vb + 6 * W));
            float s0 = (m.x - Mv[k].x) * fwc;
            float s1 = (m.y - Mv[k].y) * fwc;
            float s2 = (m.z - Mv[k].z) * fwc;
            float s3 = (m.w - Mv[k].w) * fwc;
            fs  += (s0 + s1) + (s2 + s3);
            fss += (s0 * s0 + s1 * s1) + (s2 * s2 + s3 * s3);
        }
    }

    // means assembly from partials (conflict-free strided reads)
    float ph_r = 0.f;
    float4 pvv = make_float4(0.f, 0.f, 0.f, 0.f);
    if (l < 28) {
        const int rr = l % 7, kk = l / 7;
        const float* rb = rp + rr * 28 + kk;
        float s = ((rb[0] + rb[4]) + (rb[8] + rb[12]))
                + ((rb[16] + rb[20]) + rb[24]);
        ph_r = s * (1.f / 28.f);
    }
    if (l < 7) {
        const float4* cb = (const float4*)cp;
        float4 a = cb[l];
        #pragma unroll
        for (int j = 1; j < 7; ++j) {
            float4 b = cb[l + 7 * j];
            a.x += b.x; a.y += b.y; a.z += b.z; a.w += b.w;
        }
        pvv.x = a.x * (1.f / 28.f); pvv.y = a.y * (1.f / 28.f);
        pvv.z = a.z * (1.f / 28.f); pvv.w = a.w * (1.f / 28.f);
    }

    // depthwise conv3 (zero-pad SAME) in-lane
    const float hw0 = h_w[c * 3], hw1 = h_w[c * 3 + 1], hw2 = h_w[c * 3 + 2];
    float yhv = 0.f;
    {
        float pm = __shfl_up(ph_r, 1);
        float pp = __shfl_down(ph_r, 1);
        if (l < 28) {
            float a = (l > 0) ? pm : 0.f;
            float d = (l < 27) ? pp : 0.f;
            yhv = hw0 * a + hw1 * ph_r + hw2 * d;
            yh[(size_t)plane * H + l] = yhv;
        }
    }
    const float vw0 = v_w[c * 3], vw1 = v_w[c * 3 + 1], vw2 = v_w[c * 3 + 2];
    float yvs = 0.f, yvq = 0.f;
    {
        float lf = __shfl_up(pvv.w, 1);
        float rg = __shfl_down(pvv.x, 1);
        if (l < 7) {
            float a0 = (l > 0) ? lf : 0.f;
            float d3 = (l < 6) ? rg : 0.f;
            float4 y;
            y.x = vw0 * a0    + vw1 * pvv.x + vw2 * pvv.y;
            y.y = vw0 * pvv.x + vw1 * pvv.y + vw2 * pvv.z;
            y.z = vw0 * pvv.y + vw1 * pvv.z + vw2 * pvv.w;
            y.w = vw0 * pvv.z + vw1 * pvv.w + vw2 * d3;
            ((float4*)(yv + (size_t)plane * W))[l] = y;
            yvs = (y.x + y.y) + (y.z + y.w);
            yvq = (y.x * y.x + y.y * y.y) + (y.z * y.z + y.w * y.w);
        }
    }
    float yhq = yhv * yhv;

    // 6 wave reductions on the VALU pipe
    fs = dpp_sum64(fs);  fss = dpp_sum64(fss);
    yhv = dpp_sum64(yhv); yhq = dpp_sum64(yhq);
    yvs = dpp_sum64(yvs); yvq = dpp_sum64(yvq);

    if (l == 63) {
        atomicAdd(&acc[0 * C + c], yhv);
        atomicAdd(&acc[1 * C + c], yhq);
        atomicAdd(&acc[2 * C + c], yvs);
        atomicAdd(&acc[3 * C + c], yvq);
        atomicAdd(&acc[4 * C + c], fs);
        atomicAdd(&acc[5 * C + c], fss);
    }
}

// ---------------------------------------------------------------------------
// K2: fold sums into per-channel BN scale/shift, stored padded [C][8].
// ---------------------------------------------------------------------------
__global__ __launch_bounds__(64) void k2_params(
    const float* __restrict__ acc,
    const float* __restrict__ hg, const float* __restrict__ hb,
    const float* __restrict__ vg, const float* __restrict__ vb,
    const float* __restrict__ fg, const float* __restrict__ fb,
    float* __restrict__ params)
{
    int c = blockIdx.x * 64 + threadIdx.x;
    if (c >= C) return;
    const float inv_nh = 1.f / (float)(B * H);
    const float inv_nf = 1.f / (float)(B * HW);
    float m, v, sc;
    m = acc[c] * inv_nh;
    v = acc[C + c] * inv_nh - m * m;
    sc = hg[c] * rsqrtf(v + 1e-5f);
    params[c * 8 + 0] = sc; params[c * 8 + 1] = hb[c] - m * sc;

    m = acc[2 * C + c] * inv_nh;
    v = acc[3 * C + c] * inv_nh - m * m;
    sc = vg[c] * rsqrtf(v + 1e-5f);
    params[c * 8 + 2] = sc; params[c * 8 + 3] = vb[c] - m * sc;

    m = acc[4 * C + c] * inv_nf;
    v = acc[5 * C + c] * inv_nf - m * m;
    sc = fg[c] * rsqrtf(v + 1e-5f);
    params[c * 8 + 4] = sc; params[c * 8 + 5] = fb[c] - m * sc;
}

// ---------------------------------------------------------------------------
// K3: one wave per plane; orientation dots + all four gates.
// ---------------------------------------------------------------------------
__global__ __launch_bounds__(256, 8) void k3_apply(
    const float* __restrict__ x, const float* __restrict__ f_w,
    const float* __restrict__ masks,
    const float* __restrict__ yh, const float* __restrict__ yv,
    const float* __restrict__ params,
    float* __restrict__ out)
{
    const int tid = threadIdx.x;
    const int wvi = __builtin_amdgcn_readfirstlane(tid >> 6);
    const int l   = tid & 63;
    const int plane = blockIdx.x * 4 + wvi;
    const int c = plane % C;
    const float* xp = x + (size_t)plane * HW;

    __shared__ __align__(16) float uA[4][RMROWS * W];
    float* rm  = uA[wvi];
    float* sxv = rm + 3 * W;

    const int r0 = l / 7;
    const int u  = l - r0 * 7;
    const int q  = u * 4;
    const int qL = u ? q - 4 : 0;
    const int qR = (u < 6) ? q + 4 : 24;
    const bool act = (l < 49);

    const float4 pA = *(const float4*)(params + c * 8);      // hsc,hsh,vsc,vsh
    const float2 pB = *(const float2*)(params + c * 8 + 4);  // fsc,fsh
    const float fwc = f_w[c];

    float4 Mv[4];
    float o0=0.f,o1=0.f,o2=0.f,o3=0.f,o4=0.f,o5=0.f;

    // P0: load x into regs + padded LDS; orientation dots from registers
    if (act) {
        #pragma unroll
        for (int k = 0; k < 4; ++k) {
            const int unit = l + 49 * k;
            float4 v = ((const float4*)xp)[unit];
            Mv[k] = v;
            ((float4*)sxv)[unit] = v;
            const float4* mb = (const float4*)(masks + unit * 24);
            float4 m;
            m = mb[0]; o0 += v.x*m.x + v.y*m.y + v.z*m.z + v.w*m.w;
            m = mb[1]; o1 += v.x*m.x + v.y*m.y + v.z*m.z + v.w*m.w;
            m = mb[2]; o2 += v.x*m.x + v.y*m.y + v.z*m.z + v.w*m.w;
            m = mb[3]; o3 += v.x*m.x + v.y*m.y + v.z*m.z + v.w*m.w;
            m = mb[4]; o4 += v.x*m.x + v.y*m.y + v.z*m.z + v.w*m.w;
            m = mb[5]; o5 += v.x*m.x + v.y*m.y + v.z*m.z + v.w*m.w;
        }
    }
    wave_lds_fence();

    // P1: horizontal 7-max in place (+ ghosts); DPP reductions overlap waits
    if (act) {
        #pragma unroll
        for (int k = 0; k < 4; ++k) {
            const int r = r0 + 7 * k;
            const float* row = sxv + r * W;
            float4 Lv = *(const float4*)(row + qL);
            float4 Rv = *(const float4*)(row + qR);
            float4 hv = hmax13(Mv[k], Lv, Rv);
            *(float4*)(rm + (r + 3) * W + q) = hv;
            if (k == 0 && r0 == 0) {
                *(float4*)(rm + 0 * W + q) = hv;
                *(float4*)(rm + 1 * W + q) = hv;
                *(float4*)(rm + 2 * W + q) = hv;
            }
            if (k == 3 && r0 == 6) {
                *(float4*)(rm + 31 * W + q) = hv;
                *(float4*)(rm + 32 * W + q) = hv;
                *(float4*)(rm + 33 * W + q) = hv;
            }
        }
    }
    o0 = dpp_sum64(o0); o1 = dpp_sum64(o1); o2 = dpp_sum64(o2);
    o3 = dpp_sum64(o3); o4 = dpp_sum64(o4); o5 = dpp_sum64(o5);
    const float inv784 = 1.f / (float)HW;
    float ts = sigm(rl63(o0) * inv784) + sigm(rl63(o1) * inv784)
             + sigm(rl63(o2) * inv784) + sigm(rl63(o3) * inv784)
             + sigm(rl63(o4) * inv784) + sigm(rl63(o5) * inv784);
    const float atv = ts * (1.f / 6.f);
    wave_lds_fence();

    // P2: vertical 7-max + gates + store
    if (act) {
        float4 yv4 = ((const float4*)(yv + (size_t)plane * W))[u];
        float4 av;
        av.x = sigm(pA.z * yv4.x + pA.w);
        av.y = sigm(pA.z * yv4.y + pA.w);
        av.z = sigm(pA.z * yv4.z + pA.w);
        av.w = sigm(pA.z * yv4.w + pA.w);
        float4* op = (float4*)(out + (size_t)plane * HW);
        #pragma unroll
        for (int k = 0; k < 4; ++k) {
            const int r = r0 + 7 * k;
            const float* vb = rm + r * W + q;
            float4 m = *(const float4*)vb;
            m = fmax4(m, *(const float4*)(vb + W));
            m = fmax4(m, *(const float4*)(vb + 2 * W));
            m = fmax4(m, *(const float4*)(vb + 3 * W));
            m = fmax4(m, *(const float4*)(vb + 4 * W));
            m = fmax4(m, *(const float4*)(vb + 5 * W));
            m = fmax4(m, *(const float4*)(vb + 6 * W));
            float ahk = sigm(pA.x * yh[(size_t)plane * H + r] + pA.y) * atv;
            float4 o;
            o.x = Mv[k].x * ahk * av.x * sigm(pB.x * ((m.x - Mv[k].x) * fwc) + pB.y);
            o.y = Mv[k].y * ahk * av.y * sigm(pB.x * ((m.y - Mv[k].y) * fwc) + pB.y);
            o.z = Mv[k].z * ahk * av.z * sigm(pB.x * ((m.z - Mv[k].z) * fwc) + pB.y);
            o.w = Mv[k].w * ahk * av.w * sigm(pB.x * ((m.w - Mv[k].w) * fwc) + pB.y);
            op[l + 49 * k] = o;
        }
    }
}

// ---------------------------------------------------------------------------
extern "C" void kernel_launch(void* const* d_in, const int* in_sizes, int n_in,
                              void* d_out, int out_size, void* d_ws, size_t ws_size,
                              hipStream_t stream) {
    const float* x   = (const float*)d_in[0];
    const float* h_w = (const float*)d_in[1];
    const float* h_g = (const float*)d_in[2];
    const float* h_b = (const float*)d_in[3];
    const float* v_w = (const float*)d_in[4];
    const float* v_g = (const float*)d_in[5];
    const float* v_b = (const float*)d_in[6];
    const float* f_w = (const float*)d_in[7];
    const float* f_g = (const float*)d_in[8];
    const float* f_b = (const float*)d_in[9];
    float* out = (float*)d_out;
    float* ws = (float*)d_ws;

    // workspace layout (floats)
    float* masks  = ws;                 // 196*24 = 4704 (interleaved [196][6][4])
    float* acc    = ws + 4704;          // 6*576  = 3456
    float* params = ws + 8160;          // 576*8  = 4608
    float* yh     = ws + 12768;         // B*C*H  = 2064384
    float* yv     = ws + 2077152;       // B*C*W  = 2064384

    k0_init<<<19, 256, 0, stream>>>(masks, acc);
    k1_stats<<<NPLANE / 4, 256, 0, stream>>>(x, h_w, v_w, f_w, yh, yv, acc);
    k2_params<<<9, 64, 0, stream>>>(acc, h_g, h_b, v_g, v_b, f_g, f_b, params);
    k3_apply<<<NPLANE / 4, 256, 0, stream>>>(x, f_w, masks, yh, yv, params, out);
}

// Round 9
// 200.617 us; speedup vs baseline: 1.3445x; 1.3445x over previous
//
#include <hip/hip_runtime.h>
#include <math.h>

#define B 128
#define C 576
#define H 28
#define W 28
#define HW 784
#define NPLANE (B * C)
#define RMROWS 34   // 3 ghost + 28 + 3 ghost

typedef float nfloat4 __attribute__((ext_vector_type(4)));

__device__ __forceinline__ float sigm(float z) { return 1.f / (1.f + __expf(-z)); }

__device__ __forceinline__ float4 fmax4(float4 a, float4 b) {
    a.x = fmaxf(a.x, b.x); a.y = fmaxf(a.y, b.y);
    a.z = fmaxf(a.z, b.z); a.w = fmaxf(a.w, b.w);
    return a;
}

// horizontal 7-window max for 4 px: Mv center f4, Lv left f4, Rv right f4
__device__ __forceinline__ float4 hmax13(float4 Mv, float4 Lv, float4 Rv) {
    float mm   = fmaxf(fmaxf(Mv.x, Mv.y), fmaxf(Mv.z, Mv.w));
    float l23  = fmaxf(Lv.z, Lv.w);
    float l123 = fmaxf(Lv.y, l23);
    float r01  = fmaxf(Rv.x, Rv.y);
    float r012 = fmaxf(r01, Rv.z);
    float4 o;
    o.x = fmaxf(l123, mm);
    o.y = fmaxf(l23, fmaxf(mm, Rv.x));
    o.z = fmaxf(Lv.w, fmaxf(mm, r01));
    o.w = fmaxf(mm, r012);
    return o;
}

// full 64-lane sum via DPP (VALU-only, no LDS); total lands in lane 63
__device__ __forceinline__ float dpp_sum64(float v) {
    int t;
    t = __builtin_amdgcn_update_dpp(0, __float_as_int(v), 0x111, 0xf, 0xf, true);  v += __int_as_float(t);
    t = __builtin_amdgcn_update_dpp(0, __float_as_int(v), 0x112, 0xf, 0xf, true);  v += __int_as_float(t);
    t = __builtin_amdgcn_update_dpp(0, __float_as_int(v), 0x114, 0xf, 0xf, true);  v += __int_as_float(t);
    t = __builtin_amdgcn_update_dpp(0, __float_as_int(v), 0x118, 0xf, 0xf, true);  v += __int_as_float(t);
    t = __builtin_amdgcn_update_dpp(0, __float_as_int(v), 0x142, 0xa, 0xf, false); v += __int_as_float(t);
    t = __builtin_amdgcn_update_dpp(0, __float_as_int(v), 0x143, 0xc, 0xf, false); v += __int_as_float(t);
    return v;
}

__device__ __forceinline__ float rl63(float v) {
    return __int_as_float(__builtin_amdgcn_readlane(__float_as_int(v), 63));
}

// wave-internal LDS write->read ordering (same-wave DS ops are in-order;
// fence stops compiler reordering and drains outstanding LDS ops)
__device__ __forceinline__ void wave_lds_fence() {
    asm volatile("s_waitcnt lgkmcnt(0)" ::: "memory");
    __builtin_amdgcn_sched_barrier(0);
}

// ---------------------------------------------------------------------------
// K0: zero accumulators; build orientation masks ANGLE-MAJOR [6][784]
//     (coalesced per-angle loads; r4's interleave was a stride-96B gather).
// ---------------------------------------------------------------------------
__global__ void k0_init(float* __restrict__ masks, float* __restrict__ acc) {
    int idx = blockIdx.x * 256 + threadIdx.x;
    if (idx < 6 * C) acc[idx] = 0.f;
    if (idx < 6 * HW) {
        int a = idx / HW;
        int p = idx - a * HW;
        int r = p / W;
        int col = p - r * W;
        const float degs[6] = {0.f, 30.f, 45.f, 60.f, 90.f, 135.f};
        float t = degs[a] * 0.017453292519943295f;
        float gy = -1.f + r * (2.f / 27.f);
        float gx = -1.f + col * (2.f / 27.f);
        float perp = gx * (-sinf(t)) + gy * cosf(t);
        float z = perp * (1.f / 0.3f);
        masks[idx] = expf(-0.5f * z * z);
    }
}

// ---------------------------------------------------------------------------
// K1: one wave per plane; pooling + means + conv + BN partial sums.
//     x staged inside rm's padded rows.
// ---------------------------------------------------------------------------
__global__ __launch_bounds__(256, 7) void k1_stats(
    const float* __restrict__ x,
    const float* __restrict__ h_w, const float* __restrict__ v_w,
    const float* __restrict__ f_w,
    float* __restrict__ yh, float* __restrict__ yv,
    float* __restrict__ acc)
{
    const int tid = threadIdx.x;
    const int wvi = __builtin_amdgcn_readfirstlane(tid >> 6);  // wave-uniform
    const int l   = tid & 63;
    const int plane = blockIdx.x * 4 + wvi;
    const int c = plane % C;
    const float* xp = x + (size_t)plane * HW;

    __shared__ __align__(16) float uA[4][RMROWS * W];
    __shared__ __align__(16) float cpA[4][196];
    __shared__ __align__(16) float rpA[4][196];
    float* rm  = uA[wvi];
    float* sxv = rm + 3 * W;      // x rows 0..27 live at padded rows 3..30
    float* cp  = cpA[wvi];
    float* rp  = rpA[wvi];

    const int r0 = l / 7;        // 0..6 (valid for l<49)
    const int u  = l - r0 * 7;   // column group 0..6
    const int q  = u * 4;
    const int qL = u ? q - 4 : 0;
    const int qR = (u < 6) ? q + 4 : 24;
    const bool act = (l < 49);

    float4 Mv[4];
    float fs = 0.f, fss = 0.f;

    // P0: load x into regs + padded LDS; col/row partials
    if (act) {
        float4 ca = make_float4(0.f, 0.f, 0.f, 0.f);
        float rw0, rw1, rw2, rw3;
        #pragma unroll
        for (int k = 0; k < 4; ++k) {
            const int unit = l + 49 * k;
            float4 v = ((const float4*)xp)[unit];
            Mv[k] = v;
            ((float4*)sxv)[unit] = v;
            ca.x += v.x; ca.y += v.y; ca.z += v.z; ca.w += v.w;
            float rs = (v.x + v.y) + (v.z + v.w);
            if (k == 0) rw0 = rs; else if (k == 1) rw1 = rs;
            else if (k == 2) rw2 = rs; else rw3 = rs;
        }
        ((float4*)cp)[l] = ca;
        ((float4*)rp)[l] = make_float4(rw0, rw1, rw2, rw3);
    }
    wave_lds_fence();

    // P1: horizontal 7-max; write in place over the row just read (+ ghosts)
    if (act) {
        #pragma unroll
        for (int k = 0; k < 4; ++k) {
            const int r = r0 + 7 * k;
            const float* row = sxv + r * W;
            float4 Lv = *(const float4*)(row + qL);
            float4 Rv = *(const float4*)(row + qR);
            float4 hv = hmax13(Mv[k], Lv, Rv);
            *(float4*)(rm + (r + 3) * W + q) = hv;
            if (k == 0 && r0 == 0) {
                *(float4*)(rm + 0 * W + q) = hv;
                *(float4*)(rm + 1 * W + q) = hv;
                *(float4*)(rm + 2 * W + q) = hv;
            }
            if (k == 3 && r0 == 6) {
                *(float4*)(rm + 31 * W + q) = hv;
                *(float4*)(rm + 32 * W + q) = hv;
                *(float4*)(rm + 33 * W + q) = hv;
            }
        }
    }
    wave_lds_fence();

    // P2: vertical 7-max (immediate offsets into padded rm) -> spots stats
    const float fwc = f_w[c];
    if (act) {
        #pragma unroll
        for (int k = 0; k < 4; ++k) {
            const int r = r0 + 7 * k;
            const float* vb = rm + r * W + q;
            float4 m = *(const float4*)vb;
            m = fmax4(m, *(const float4*)(vb + W));
            m = fmax4(m, *(const float4*)(vb + 2 * W));
            m = fmax4(m, *(const float4*)(vb + 3 * W));
            m = fmax4(m, *(const float4*)(vb + 4 * W));
            m = fmax4(m, *(const float4*)(vb + 5 * W));
            m = fmax4(m, *(const float4*)(vb + 6 * W));
            float s0 = (m.x - Mv[k].x) * fwc;
            float s1 = (m.y - Mv[k].y) * fwc;
            float s2 = (m.z - Mv[k].z) * fwc;
            float s3 = (m.w - Mv[k].w) * fwc;
            fs  += (s0 + s1) + (s2 + s3);
            fss += (s0 * s0 + s1 * s1) + (s2 * s2 + s3 * s3);
        }
    }

    // means assembly from partials (conflict-free strided reads)
    float ph_r = 0.f;
    float4 pvv = make_float4(0.f, 0.f, 0.f, 0.f);
    if (l < 28) {
        const int rr = l % 7, kk = l / 7;
        const float* rb = rp + rr * 28 + kk;
        float s = ((rb[0] + rb[4]) + (rb[8] + rb[12]))
                + ((rb[16] + rb[20]) + rb[24]);
        ph_r = s * (1.f / 28.f);
    }
    if (l < 7) {
        const float4* cb = (const float4*)cp;
        float4 a = cb[l];
        #pragma unroll
        for (int j = 1; j < 7; ++j) {
            float4 b = cb[l + 7 * j];
            a.x += b.x; a.y += b.y; a.z += b.z; a.w += b.w;
        }
        pvv.x = a.x * (1.f / 28.f); pvv.y = a.y * (1.f / 28.f);
        pvv.z = a.z * (1.f / 28.f); pvv.w = a.w * (1.f / 28.f);
    }

    // depthwise conv3 (zero-pad SAME) in-lane
    const float hw0 = h_w[c * 3], hw1 = h_w[c * 3 + 1], hw2 = h_w[c * 3 + 2];
    float yhv = 0.f;
    {
        float pm = __shfl_up(ph_r, 1);
        float pp = __shfl_down(ph_r, 1);
        if (l < 28) {
            float a = (l > 0) ? pm : 0.f;
            float d = (l < 27) ? pp : 0.f;
            yhv = hw0 * a + hw1 * ph_r + hw2 * d;
            yh[(size_t)plane * H + l] = yhv;
        }
    }
    const float vw0 = v_w[c * 3], vw1 = v_w[c * 3 + 1], vw2 = v_w[c * 3 + 2];
    float yvs = 0.f, yvq = 0.f;
    {
        float lf = __shfl_up(pvv.w, 1);
        float rg = __shfl_down(pvv.x, 1);
        if (l < 7) {
            float a0 = (l > 0) ? lf : 0.f;
            float d3 = (l < 6) ? rg : 0.f;
            float4 y;
            y.x = vw0 * a0    + vw1 * pvv.x + vw2 * pvv.y;
            y.y = vw0 * pvv.x + vw1 * pvv.y + vw2 * pvv.z;
            y.z = vw0 * pvv.y + vw1 * pvv.z + vw2 * pvv.w;
            y.w = vw0 * pvv.z + vw1 * pvv.w + vw2 * d3;
            ((float4*)(yv + (size_t)plane * W))[l] = y;
            yvs = (y.x + y.y) + (y.z + y.w);
            yvq = (y.x * y.x + y.y * y.y) + (y.z * y.z + y.w * y.w);
        }
    }
    float yhq = yhv * yhv;

    // 6 wave reductions on the VALU pipe
    fs = dpp_sum64(fs);  fss = dpp_sum64(fss);
    yhv = dpp_sum64(yhv); yhq = dpp_sum64(yhq);
    yvs = dpp_sum64(yvs); yvq = dpp_sum64(yvq);

    if (l == 63) {
        atomicAdd(&acc[0 * C + c], yhv);
        atomicAdd(&acc[1 * C + c], yhq);
        atomicAdd(&acc[2 * C + c], yvs);
        atomicAdd(&acc[3 * C + c], yvq);
        atomicAdd(&acc[4 * C + c], fs);
        atomicAdd(&acc[5 * C + c], fss);
    }
}

// ---------------------------------------------------------------------------
// K2: fold sums into per-channel BN scale/shift, stored padded [C][8].
// ---------------------------------------------------------------------------
__global__ __launch_bounds__(64) void k2_params(
    const float* __restrict__ acc,
    const float* __restrict__ hg, const float* __restrict__ hb,
    const float* __restrict__ vg, const float* __restrict__ vb,
    const float* __restrict__ fg, const float* __restrict__ fb,
    float* __restrict__ params)
{
    int c = blockIdx.x * 64 + threadIdx.x;
    if (c >= C) return;
    const float inv_nh = 1.f / (float)(B * H);
    const float inv_nf = 1.f / (float)(B * HW);
    float m, v, sc;
    m = acc[c] * inv_nh;
    v = acc[C + c] * inv_nh - m * m;
    sc = hg[c] * rsqrtf(v + 1e-5f);
    params[c * 8 + 0] = sc; params[c * 8 + 1] = hb[c] - m * sc;

    m = acc[2 * C + c] * inv_nh;
    v = acc[3 * C + c] * inv_nh - m * m;
    sc = vg[c] * rsqrtf(v + 1e-5f);
    params[c * 8 + 2] = sc; params[c * 8 + 3] = vb[c] - m * sc;

    m = acc[4 * C + c] * inv_nf;
    v = acc[5 * C + c] * inv_nf - m * m;
    sc = fg[c] * rsqrtf(v + 1e-5f);
    params[c * 8 + 4] = sc; params[c * 8 + 5] = fb[c] - m * sc;
}

// ---------------------------------------------------------------------------
// K3: one wave per plane; orientation dots (coalesced) + all four gates.
// ---------------------------------------------------------------------------
__global__ __launch_bounds__(256, 8) void k3_apply(
    const float* __restrict__ x, const float* __restrict__ f_w,
    const float* __restrict__ masks,
    const float* __restrict__ yh, const float* __restrict__ yv,
    const float* __restrict__ params,
    float* __restrict__ out)
{
    const int tid = threadIdx.x;
    const int wvi = __builtin_amdgcn_readfirstlane(tid >> 6);
    const int l   = tid & 63;
    const int plane = blockIdx.x * 4 + wvi;
    const int c = plane % C;
    const float* xp = x + (size_t)plane * HW;

    __shared__ __align__(16) float uA[4][RMROWS * W];
    float* rm  = uA[wvi];
    float* sxv = rm + 3 * W;

    const int r0 = l / 7;
    const int u  = l - r0 * 7;
    const int q  = u * 4;
    const int qL = u ? q - 4 : 0;
    const int qR = (u < 6) ? q + 4 : 24;
    const bool act = (l < 49);

    const float4 pA = *(const float4*)(params + c * 8);      // hsc,hsh,vsc,vsh
    const float2 pB = *(const float2*)(params + c * 8 + 4);  // fsc,fsh
    const float fwc = f_w[c];

    // angle-major mask bases (SGPR-uniform; per-angle loads are coalesced)
    const float4* mk0 = (const float4*)(masks);
    const float4* mk1 = (const float4*)(masks + HW);
    const float4* mk2 = (const float4*)(masks + 2 * HW);
    const float4* mk3 = (const float4*)(masks + 3 * HW);
    const float4* mk4 = (const float4*)(masks + 4 * HW);
    const float4* mk5 = (const float4*)(masks + 5 * HW);

    float4 Mv[4];
    float o0=0.f,o1=0.f,o2=0.f,o3=0.f,o4=0.f,o5=0.f;

    // P0: load x into regs + padded LDS; orientation dots from registers
    if (act) {
        #pragma unroll
        for (int k = 0; k < 4; ++k) {
            const int unit = l + 49 * k;
            float4 v = ((const float4*)xp)[unit];
            Mv[k] = v;
            ((float4*)sxv)[unit] = v;
            float4 m;
            m = mk0[unit]; o0 += v.x*m.x + v.y*m.y + v.z*m.z + v.w*m.w;
            m = mk1[unit]; o1 += v.x*m.x + v.y*m.y + v.z*m.z + v.w*m.w;
            m = mk2[unit]; o2 += v.x*m.x + v.y*m.y + v.z*m.z + v.w*m.w;
            m = mk3[unit]; o3 += v.x*m.x + v.y*m.y + v.z*m.z + v.w*m.w;
            m = mk4[unit]; o4 += v.x*m.x + v.y*m.y + v.z*m.z + v.w*m.w;
            m = mk5[unit]; o5 += v.x*m.x + v.y*m.y + v.z*m.z + v.w*m.w;
        }
    }
    wave_lds_fence();

    // P1: horizontal 7-max in place (+ ghosts); DPP reductions overlap waits
    if (act) {
        #pragma unroll
        for (int k = 0; k < 4; ++k) {
            const int r = r0 + 7 * k;
            const float* row = sxv + r * W;
            float4 Lv = *(const float4*)(row + qL);
            float4 Rv = *(const float4*)(row + qR);
            float4 hv = hmax13(Mv[k], Lv, Rv);
            *(float4*)(rm + (r + 3) * W + q) = hv;
            if (k == 0 && r0 == 0) {
                *(float4*)(rm + 0 * W + q) = hv;
                *(float4*)(rm + 1 * W + q) = hv;
                *(float4*)(rm + 2 * W + q) = hv;
            }
            if (k == 3 && r0 == 6) {
                *(float4*)(rm + 31 * W + q) = hv;
                *(float4*)(rm + 32 * W + q) = hv;
                *(float4*)(rm + 33 * W + q) = hv;
            }
        }
    }
    o0 = dpp_sum64(o0); o1 = dpp_sum64(o1); o2 = dpp_sum64(o2);
    o3 = dpp_sum64(o3); o4 = dpp_sum64(o4); o5 = dpp_sum64(o5);
    const float inv784 = 1.f / (float)HW;
    float ts = sigm(rl63(o0) * inv784) + sigm(rl63(o1) * inv784)
             + sigm(rl63(o2) * inv784) + sigm(rl63(o3) * inv784)
             + sigm(rl63(o4) * inv784) + sigm(rl63(o5) * inv784);
    const float atv = ts * (1.f / 6.f);
    wave_lds_fence();

    // P2: vertical 7-max + gates + nontemporal store
    if (act) {
        float4 yv4 = ((const float4*)(yv + (size_t)plane * W))[u];
        float4 av;
        av.x = sigm(pA.z * yv4.x + pA.w);
        av.y = sigm(pA.z * yv4.y + pA.w);
        av.z = sigm(pA.z * yv4.z + pA.w);
        av.w = sigm(pA.z * yv4.w + pA.w);
        nfloat4* op = (nfloat4*)(out + (size_t)plane * HW);
        #pragma unroll
        for (int k = 0; k < 4; ++k) {
            const int r = r0 + 7 * k;
            const float* vb = rm + r * W + q;
            float4 m = *(const float4*)vb;
            m = fmax4(m, *(const float4*)(vb + W));
            m = fmax4(m, *(const float4*)(vb + 2 * W));
            m = fmax4(m, *(const float4*)(vb + 3 * W));
            m = fmax4(m, *(const float4*)(vb + 4 * W));
            m = fmax4(m, *(const float4*)(vb + 5 * W));
            m = fmax4(m, *(const float4*)(vb + 6 * W));
            float ahk = sigm(pA.x * yh[(size_t)plane * H + r] + pA.y) * atv;
            nfloat4 o;
            o.x = Mv[k].x * ahk * av.x * sigm(pB.x * ((m.x - Mv[k].x) * fwc) + pB.y);
            o.y = Mv[k].y * ahk * av.y * sigm(pB.x * ((m.y - Mv[k].y) * fwc) + pB.y);
            o.z = Mv[k].z * ahk * av.z * sigm(pB.x * ((m.z - Mv[k].z) * fwc) + pB.y);
            o.w = Mv[k].w * ahk * av.w * sigm(pB.x * ((m.w - Mv[k].w) * fwc) + pB.y);
            __builtin_nontemporal_store(o, &op[l + 49 * k]);
        }
    }
}

// ---------------------------------------------------------------------------
extern "C" void kernel_launch(void* const* d_in, const int* in_sizes, int n_in,
                              void* d_out, int out_size, void* d_ws, size_t ws_size,
                              hipStream_t stream) {
    const float* x   = (const float*)d_in[0];
    const float* h_w = (const float*)d_in[1];
    const float* h_g = (const float*)d_in[2];
    const float* h_b = (const float*)d_in[3];
    const float* v_w = (const float*)d_in[4];
    const float* v_g = (const float*)d_in[5];
    const float* v_b = (const float*)d_in[6];
    const float* f_w = (const float*)d_in[7];
    const float* f_g = (const float*)d_in[8];
    const float* f_b = (const float*)d_in[9];
    float* out = (float*)d_out;
    float* ws = (float*)d_ws;

    // workspace layout (floats)
    float* masks  = ws;                 // 6*784  = 4704 (angle-major [6][784])
    float* acc    = ws + 4704;          // 6*576  = 3456
    float* params = ws + 8160;          // 576*8  = 4608
    float* yh     = ws + 12768;         // B*C*H  = 2064384
    float* yv     = ws + 2077152;       // B*C*W  = 2064384

    k0_init<<<19, 256, 0, stream>>>(masks, acc);
    k1_stats<<<NPLANE / 4, 256, 0, stream>>>(x, h_w, v_w, f_w, yh, yv, acc);
    k2_params<<<9, 64, 0, stream>>>(acc, h_g, h_b, v_g, v_b, f_g, f_b, params);
    k3_apply<<<NPLANE / 4, 256, 0, stream>>>(x, f_w, masks, yh, yv, params, out);
}

// Round 10
// 190.286 us; speedup vs baseline: 1.4175x; 1.0543x over previous
//
#include <hip/hip_runtime.h>
#include <math.h>

#define B 128
#define C 576
#define H 28
#define W 28
#define HW 784
#define NPLANE (B * C)
#define RMROWS 34   // 3 ghost + 28 + 3 ghost

typedef float nfloat4 __attribute__((ext_vector_type(4)));

__device__ __forceinline__ float sigm(float z) { return 1.f / (1.f + __expf(-z)); }

__device__ __forceinline__ float4 fmax4(float4 a, float4 b) {
    a.x = fmaxf(a.x, b.x); a.y = fmaxf(a.y, b.y);
    a.z = fmaxf(a.z, b.z); a.w = fmaxf(a.w, b.w);
    return a;
}

// horizontal 7-window max for 4 px: Mv center f4, Lv left f4, Rv right f4
__device__ __forceinline__ float4 hmax13(float4 Mv, float4 Lv, float4 Rv) {
    float mm   = fmaxf(fmaxf(Mv.x, Mv.y), fmaxf(Mv.z, Mv.w));
    float l23  = fmaxf(Lv.z, Lv.w);
    float l123 = fmaxf(Lv.y, l23);
    float r01  = fmaxf(Rv.x, Rv.y);
    float r012 = fmaxf(r01, Rv.z);
    float4 o;
    o.x = fmaxf(l123, mm);
    o.y = fmaxf(l23, fmaxf(mm, Rv.x));
    o.z = fmaxf(Lv.w, fmaxf(mm, r01));
    o.w = fmaxf(mm, r012);
    return o;
}

// full 64-lane sum via DPP (VALU-only, no LDS); total lands in lane 63
__device__ __forceinline__ float dpp_sum64(float v) {
    int t;
    t = __builtin_amdgcn_update_dpp(0, __float_as_int(v), 0x111, 0xf, 0xf, true);  v += __int_as_float(t);
    t = __builtin_amdgcn_update_dpp(0, __float_as_int(v), 0x112, 0xf, 0xf, true);  v += __int_as_float(t);
    t = __builtin_amdgcn_update_dpp(0, __float_as_int(v), 0x114, 0xf, 0xf, true);  v += __int_as_float(t);
    t = __builtin_amdgcn_update_dpp(0, __float_as_int(v), 0x118, 0xf, 0xf, true);  v += __int_as_float(t);
    t = __builtin_amdgcn_update_dpp(0, __float_as_int(v), 0x142, 0xa, 0xf, false); v += __int_as_float(t);
    t = __builtin_amdgcn_update_dpp(0, __float_as_int(v), 0x143, 0xc, 0xf, false); v += __int_as_float(t);
    return v;
}

// wave-internal LDS write->read ordering (same-wave DS ops are in-order;
// fence stops compiler reordering and drains outstanding LDS ops)
__device__ __forceinline__ void wave_lds_fence() {
    asm volatile("s_waitcnt lgkmcnt(0)" ::: "memory");
    __builtin_amdgcn_sched_barrier(0);
}

// ---------------------------------------------------------------------------
// K0: zero accumulators; build orientation masks ANGLE-MAJOR [6][784].
// ---------------------------------------------------------------------------
__global__ void k0_init(float* __restrict__ masks, float* __restrict__ acc) {
    int idx = blockIdx.x * 256 + threadIdx.x;
    if (idx < 6 * C) acc[idx] = 0.f;
    if (idx < 6 * HW) {
        int a = idx / HW;
        int p = idx - a * HW;
        int r = p / W;
        int col = p - r * W;
        const float degs[6] = {0.f, 30.f, 45.f, 60.f, 90.f, 135.f};
        float t = degs[a] * 0.017453292519943295f;
        float gy = -1.f + r * (2.f / 27.f);
        float gx = -1.f + col * (2.f / 27.f);
        float perp = gx * (-sinf(t)) + gy * cosf(t);
        float z = perp * (1.f / 0.3f);
        masks[idx] = expf(-0.5f * z * z);
    }
}

// ---------------------------------------------------------------------------
// K1: one wave per plane; pooling + means + conv + BN partial sums +
//     orientation (coalesced angle-major masks; dots+DPP right after P0 so
//     the o-registers die early and VGPR stays at the 64 quantum).
// ---------------------------------------------------------------------------
__global__ __launch_bounds__(256, 7) void k1_stats(
    const float* __restrict__ x,
    const float* __restrict__ h_w, const float* __restrict__ v_w,
    const float* __restrict__ f_w, const float* __restrict__ masks,
    float* __restrict__ yh, float* __restrict__ yv,
    float* __restrict__ at, float* __restrict__ acc)
{
    const int tid = threadIdx.x;
    const int wvi = __builtin_amdgcn_readfirstlane(tid >> 6);  // wave-uniform
    const int l   = tid & 63;
    const int plane = blockIdx.x * 4 + wvi;
    const int c = plane % C;
    const float* xp = x + (size_t)plane * HW;

    __shared__ __align__(16) float uA[4][RMROWS * W];
    __shared__ __align__(16) float cpA[4][196];
    __shared__ __align__(16) float rpA[4][196];
    float* rm  = uA[wvi];
    float* sxv = rm + 3 * W;      // x rows 0..27 live at padded rows 3..30
    float* cp  = cpA[wvi];
    float* rp  = rpA[wvi];

    const int r0 = l / 7;        // 0..6 (valid for l<49)
    const int u  = l - r0 * 7;   // column group 0..6
    const int q  = u * 4;
    const int qL = u ? q - 4 : 0;
    const int qR = (u < 6) ? q + 4 : 24;
    const bool act = (l < 49);

    // angle-major mask bases (SGPR-uniform; per-angle loads are coalesced)
    const float4* mk0 = (const float4*)(masks);
    const float4* mk1 = (const float4*)(masks + HW);
    const float4* mk2 = (const float4*)(masks + 2 * HW);
    const float4* mk3 = (const float4*)(masks + 3 * HW);
    const float4* mk4 = (const float4*)(masks + 4 * HW);
    const float4* mk5 = (const float4*)(masks + 5 * HW);

    float4 Mv[4];
    float fs = 0.f, fss = 0.f;

    // P0: load x into regs + padded LDS; col/row partials; orientation dots
    {
        float o0=0.f,o1=0.f,o2=0.f,o3=0.f,o4=0.f,o5=0.f;
        if (act) {
            float4 ca = make_float4(0.f, 0.f, 0.f, 0.f);
            float rw0, rw1, rw2, rw3;
            #pragma unroll
            for (int k = 0; k < 4; ++k) {
                const int unit = l + 49 * k;
                float4 v = ((const float4*)xp)[unit];
                Mv[k] = v;
                ((float4*)sxv)[unit] = v;
                ca.x += v.x; ca.y += v.y; ca.z += v.z; ca.w += v.w;
                float rs = (v.x + v.y) + (v.z + v.w);
                if (k == 0) rw0 = rs; else if (k == 1) rw1 = rs;
                else if (k == 2) rw2 = rs; else rw3 = rs;
                float4 m;
                m = mk0[unit]; o0 += v.x*m.x + v.y*m.y + v.z*m.z + v.w*m.w;
                m = mk1[unit]; o1 += v.x*m.x + v.y*m.y + v.z*m.z + v.w*m.w;
                m = mk2[unit]; o2 += v.x*m.x + v.y*m.y + v.z*m.z + v.w*m.w;
                m = mk3[unit]; o3 += v.x*m.x + v.y*m.y + v.z*m.z + v.w*m.w;
                m = mk4[unit]; o4 += v.x*m.x + v.y*m.y + v.z*m.z + v.w*m.w;
                m = mk5[unit]; o5 += v.x*m.x + v.y*m.y + v.z*m.z + v.w*m.w;
            }
            ((float4*)cp)[l] = ca;
            ((float4*)rp)[l] = make_float4(rw0, rw1, rw2, rw3);
        }
        // orientation reduction now (o-regs die here; hides the LDS drain)
        o0 = dpp_sum64(o0); o1 = dpp_sum64(o1); o2 = dpp_sum64(o2);
        o3 = dpp_sum64(o3); o4 = dpp_sum64(o4); o5 = dpp_sum64(o5);
        if (l == 63) {
            const float inv784 = 1.f / (float)HW;
            float t = sigm(o0 * inv784) + sigm(o1 * inv784) + sigm(o2 * inv784)
                    + sigm(o3 * inv784) + sigm(o4 * inv784) + sigm(o5 * inv784);
            at[plane] = t * (1.f / 6.f);
        }
    }
    wave_lds_fence();

    // P1: horizontal 7-max; write in place over the row just read (+ ghosts)
    if (act) {
        #pragma unroll
        for (int k = 0; k < 4; ++k) {
            const int r = r0 + 7 * k;
            const float* row = sxv + r * W;
            float4 Lv = *(const float4*)(row + qL);
            float4 Rv = *(const float4*)(row + qR);
            float4 hv = hmax13(Mv[k], Lv, Rv);
            *(float4*)(rm + (r + 3) * W + q) = hv;
            if (k == 0 && r0 == 0) {
                *(float4*)(rm + 0 * W + q) = hv;
                *(float4*)(rm + 1 * W + q) = hv;
                *(float4*)(rm + 2 * W + q) = hv;
            }
            if (k == 3 && r0 == 6) {
                *(float4*)(rm + 31 * W + q) = hv;
                *(float4*)(rm + 32 * W + q) = hv;
                *(float4*)(rm + 33 * W + q) = hv;
            }
        }
    }
    wave_lds_fence();

    // P2: vertical 7-max -> RAW spot moments (fwc folded in once at the end)
    if (act) {
        #pragma unroll
        for (int k = 0; k < 4; ++k) {
            const int r = r0 + 7 * k;
            const float* vb = rm + r * W + q;
            float4 m = *(const float4*)vb;
            m = fmax4(m, *(const float4*)(vb + W));
            m = fmax4(m, *(const float4*)(vb + 2 * W));
            m = fmax4(m, *(const float4*)(vb + 3 * W));
            m = fmax4(m, *(const float4*)(vb + 4 * W));
            m = fmax4(m, *(const float4*)(vb + 5 * W));
            m = fmax4(m, *(const float4*)(vb + 6 * W));
            float s0 = m.x - Mv[k].x;
            float s1 = m.y - Mv[k].y;
            float s2 = m.z - Mv[k].z;
            float s3 = m.w - Mv[k].w;
            fs  += (s0 + s1) + (s2 + s3);
            fss += (s0 * s0 + s1 * s1) + (s2 * s2 + s3 * s3);
        }
    }

    // means assembly from partials (conflict-free strided reads)
    float ph_r = 0.f;
    float4 pvv = make_float4(0.f, 0.f, 0.f, 0.f);
    if (l < 28) {
        const int rr = l % 7, kk = l / 7;
        const float* rb = rp + rr * 28 + kk;
        float s = ((rb[0] + rb[4]) + (rb[8] + rb[12]))
                + ((rb[16] + rb[20]) + rb[24]);
        ph_r = s * (1.f / 28.f);
    }
    if (l < 7) {
        const float4* cb = (const float4*)cp;
        float4 a = cb[l];
        #pragma unroll
        for (int j = 1; j < 7; ++j) {
            float4 b = cb[l + 7 * j];
            a.x += b.x; a.y += b.y; a.z += b.z; a.w += b.w;
        }
        pvv.x = a.x * (1.f / 28.f); pvv.y = a.y * (1.f / 28.f);
        pvv.z = a.z * (1.f / 28.f); pvv.w = a.w * (1.f / 28.f);
    }

    // depthwise conv3 (zero-pad SAME) in-lane
    const float hw0 = h_w[c * 3], hw1 = h_w[c * 3 + 1], hw2 = h_w[c * 3 + 2];
    float yhv = 0.f;
    {
        float pm = __shfl_up(ph_r, 1);
        float pp = __shfl_down(ph_r, 1);
        if (l < 28) {
            float a = (l > 0) ? pm : 0.f;
            float d = (l < 27) ? pp : 0.f;
            yhv = hw0 * a + hw1 * ph_r + hw2 * d;
            yh[(size_t)plane * H + l] = yhv;
        }
    }
    const float vw0 = v_w[c * 3], vw1 = v_w[c * 3 + 1], vw2 = v_w[c * 3 + 2];
    float yvs = 0.f, yvq = 0.f;
    {
        float lf = __shfl_up(pvv.w, 1);
        float rg = __shfl_down(pvv.x, 1);
        if (l < 7) {
            float a0 = (l > 0) ? lf : 0.f;
            float d3 = (l < 6) ? rg : 0.f;
            float4 y;
            y.x = vw0 * a0    + vw1 * pvv.x + vw2 * pvv.y;
            y.y = vw0 * pvv.x + vw1 * pvv.y + vw2 * pvv.z;
            y.z = vw0 * pvv.y + vw1 * pvv.z + vw2 * pvv.w;
            y.w = vw0 * pvv.z + vw1 * pvv.w + vw2 * d3;
            ((float4*)(yv + (size_t)plane * W))[l] = y;
            yvs = (y.x + y.y) + (y.z + y.w);
            yvq = (y.x * y.x + y.y * y.y) + (y.z * y.z + y.w * y.w);
        }
    }
    float yhq = yhv * yhv;

    // 6 wave reductions on the VALU pipe
    fs = dpp_sum64(fs);  fss = dpp_sum64(fss);
    yhv = dpp_sum64(yhv); yhq = dpp_sum64(yhq);
    yvs = dpp_sum64(yvs); yvq = dpp_sum64(yvq);

    if (l == 63) {
        const float fwc = f_w[c];
        atomicAdd(&acc[0 * C + c], yhv);
        atomicAdd(&acc[1 * C + c], yhq);
        atomicAdd(&acc[2 * C + c], yvs);
        atomicAdd(&acc[3 * C + c], yvq);
        atomicAdd(&acc[4 * C + c], fs * fwc);
        atomicAdd(&acc[5 * C + c], fss * fwc * fwc);
    }
}

// ---------------------------------------------------------------------------
// K2: fold sums into per-channel BN scale/shift, stored padded [C][8].
//     f-gate scale is pre-multiplied by f_w (k3 never touches f_w).
// ---------------------------------------------------------------------------
__global__ __launch_bounds__(64) void k2_params(
    const float* __restrict__ acc, const float* __restrict__ f_w,
    const float* __restrict__ hg, const float* __restrict__ hb,
    const float* __restrict__ vg, const float* __restrict__ vb,
    const float* __restrict__ fg, const float* __restrict__ fb,
    float* __restrict__ params)
{
    int c = blockIdx.x * 64 + threadIdx.x;
    if (c >= C) return;
    const float inv_nh = 1.f / (float)(B * H);
    const float inv_nf = 1.f / (float)(B * HW);
    float m, v, sc;
    m = acc[c] * inv_nh;
    v = acc[C + c] * inv_nh - m * m;
    sc = hg[c] * rsqrtf(v + 1e-5f);
    params[c * 8 + 0] = sc; params[c * 8 + 1] = hb[c] - m * sc;

    m = acc[2 * C + c] * inv_nh;
    v = acc[3 * C + c] * inv_nh - m * m;
    sc = vg[c] * rsqrtf(v + 1e-5f);
    params[c * 8 + 2] = sc; params[c * 8 + 3] = vb[c] - m * sc;

    m = acc[4 * C + c] * inv_nf;
    v = acc[5 * C + c] * inv_nf - m * m;
    sc = fg[c] * rsqrtf(v + 1e-5f);
    params[c * 8 + 4] = sc * f_w[c];       // folded: acts on raw (max - x)
    params[c * 8 + 5] = fb[c] - m * sc;
}

// ---------------------------------------------------------------------------
// K3: one wave per plane; pooling recompute + all four gates (no masks).
// ---------------------------------------------------------------------------
__global__ __launch_bounds__(256, 8) void k3_apply(
    const float* __restrict__ x,
    const float* __restrict__ yh, const float* __restrict__ yv,
    const float* __restrict__ at, const float* __restrict__ params,
    float* __restrict__ out)
{
    const int tid = threadIdx.x;
    const int wvi = __builtin_amdgcn_readfirstlane(tid >> 6);
    const int l   = tid & 63;
    const int plane = blockIdx.x * 4 + wvi;
    const int c = plane % C;
    const float* xp = x + (size_t)plane * HW;

    __shared__ __align__(16) float uA[4][RMROWS * W];
    float* rm  = uA[wvi];
    float* sxv = rm + 3 * W;

    const int r0 = l / 7;
    const int u  = l - r0 * 7;
    const int q  = u * 4;
    const int qL = u ? q - 4 : 0;
    const int qR = (u < 6) ? q + 4 : 24;
    const bool act = (l < 49);

    const float4 pA = *(const float4*)(params + c * 8);      // hsc,hsh,vsc,vsh
    const float2 pB = *(const float2*)(params + c * 8 + 4);  // fsc*fwc, fsh
    const float atv = at[plane];

    float4 Mv[4];

    // P0: load x into regs + padded LDS
    if (act) {
        #pragma unroll
        for (int k = 0; k < 4; ++k) {
            const int unit = l + 49 * k;
            Mv[k] = ((const float4*)xp)[unit];
            ((float4*)sxv)[unit] = Mv[k];
        }
    }
    wave_lds_fence();

    // P1: horizontal 7-max in place (+ ghosts)
    if (act) {
        #pragma unroll
        for (int k = 0; k < 4; ++k) {
            const int r = r0 + 7 * k;
            const float* row = sxv + r * W;
            float4 Lv = *(const float4*)(row + qL);
            float4 Rv = *(const float4*)(row + qR);
            float4 hv = hmax13(Mv[k], Lv, Rv);
            *(float4*)(rm + (r + 3) * W + q) = hv;
            if (k == 0 && r0 == 0) {
                *(float4*)(rm + 0 * W + q) = hv;
                *(float4*)(rm + 1 * W + q) = hv;
                *(float4*)(rm + 2 * W + q) = hv;
            }
            if (k == 3 && r0 == 6) {
                *(float4*)(rm + 31 * W + q) = hv;
                *(float4*)(rm + 32 * W + q) = hv;
                *(float4*)(rm + 33 * W + q) = hv;
            }
        }
    }
    wave_lds_fence();

    // P2: vertical 7-max + gates + nontemporal store
    if (act) {
        float4 yv4 = ((const float4*)(yv + (size_t)plane * W))[u];
        float4 av;
        av.x = sigm(pA.z * yv4.x + pA.w);
        av.y = sigm(pA.z * yv4.y + pA.w);
        av.z = sigm(pA.z * yv4.z + pA.w);
        av.w = sigm(pA.z * yv4.w + pA.w);
        nfloat4* op = (nfloat4*)(out + (size_t)plane * HW);
        #pragma unroll
        for (int k = 0; k < 4; ++k) {
            const int r = r0 + 7 * k;
            const float* vb = rm + r * W + q;
            float4 m = *(const float4*)vb;
            m = fmax4(m, *(const float4*)(vb + W));
            m = fmax4(m, *(const float4*)(vb + 2 * W));
            m = fmax4(m, *(const float4*)(vb + 3 * W));
            m = fmax4(m, *(const float4*)(vb + 4 * W));
            m = fmax4(m, *(const float4*)(vb + 5 * W));
            m = fmax4(m, *(const float4*)(vb + 6 * W));
            float ahk = sigm(pA.x * yh[(size_t)plane * H + r] + pA.y) * atv;
            nfloat4 o;
            // af gate: z = fsc'*(m - x) + fsh  ->  fma(fsc', m, fma(-fsc', x, fsh))
            o.x = Mv[k].x * ahk * av.x * sigm(fmaf(pB.x, m.x, fmaf(-pB.x, Mv[k].x, pB.y)));
            o.y = Mv[k].y * ahk * av.y * sigm(fmaf(pB.x, m.y, fmaf(-pB.x, Mv[k].y, pB.y)));
            o.z = Mv[k].z * ahk * av.z * sigm(fmaf(pB.x, m.z, fmaf(-pB.x, Mv[k].z, pB.y)));
            o.w = Mv[k].w * ahk * av.w * sigm(fmaf(pB.x, m.w, fmaf(-pB.x, Mv[k].w, pB.y)));
            __builtin_nontemporal_store(o, &op[l + 49 * k]);
        }
    }
}

// ---------------------------------------------------------------------------
extern "C" void kernel_launch(void* const* d_in, const int* in_sizes, int n_in,
                              void* d_out, int out_size, void* d_ws, size_t ws_size,
                              hipStream_t stream) {
    const float* x   = (const float*)d_in[0];
    const float* h_w = (const float*)d_in[1];
    const float* h_g = (const float*)d_in[2];
    const float* h_b = (const float*)d_in[3];
    const float* v_w = (const float*)d_in[4];
    const float* v_g = (const float*)d_in[5];
    const float* v_b = (const float*)d_in[6];
    const float* f_w = (const float*)d_in[7];
    const float* f_g = (const float*)d_in[8];
    const float* f_b = (const float*)d_in[9];
    float* out = (float*)d_out;
    float* ws = (float*)d_ws;

    // workspace layout (floats)
    float* masks  = ws;                 // 6*784  = 4704 (angle-major [6][784])
    float* acc    = ws + 4704;          // 6*576  = 3456
    float* params = ws + 8160;          // 576*8  = 4608
    float* at     = ws + 12768;         // B*C    = 73728
    float* yh     = ws + 86496;         // B*C*H  = 2064384
    float* yv     = ws + 2150880;       // B*C*W  = 2064384

    k0_init<<<19, 256, 0, stream>>>(masks, acc);
    k1_stats<<<NPLANE / 4, 256, 0, stream>>>(x, h_w, v_w, f_w, masks, yh, yv, at, acc);
    k2_params<<<9, 64, 0, stream>>>(acc, f_w, h_g, h_b, v_g, v_b, f_g, f_b, params);
    k3_apply<<<NPLANE / 4, 256, 0, stream>>>(x, yh, yv, at, params, out);
}